// Round 10
// baseline (466.101 us; speedup 1.0000x reference)
//
#include <hip/hip_runtime.h>
#include <hip/hip_cooperative_groups.h>
#include <hip/hip_bf16.h>
#include <stdint.h>

namespace cg = cooperative_groups;

typedef unsigned short u16;
typedef unsigned int   u32;
typedef short s16x8 __attribute__((ext_vector_type(8)));
typedef float f32x4 __attribute__((ext_vector_type(4)));

#define LDP 33409

__device__ __forceinline__ u16 f2bf(float f) {
    union { float f; u32 u; } v; v.f = f;
    u32 r = v.u + 0x7fffu + ((v.u >> 16) & 1u);
    return (u16)(r >> 16);
}
__device__ __forceinline__ float bf2f(u16 h) {
    union { u32 u; float f; } v; v.u = ((u32)h) << 16;
    return v.f;
}
__device__ __forceinline__ float fast_tanh(float x) {
    float e = __expf(2.0f * x);
    return 1.0f - 2.0f / (e + 1.0f);
}
__device__ __forceinline__ f32x4 MFMA(s16x8 a, s16x8 b, f32x4 c) {
    return __builtin_amdgcn_mfma_f32_16x16x32_bf16(a, b, c, 0, 0, 0);
}
__device__ __forceinline__ void gload_lds16(const void* g, void* l) {
    __builtin_amdgcn_global_load_lds(
        (const __attribute__((address_space(1))) u32*)(uintptr_t)g,
        (__attribute__((address_space(3))) u32*)(uintptr_t)l, 16, 0, 0);
}

struct Args {
    const float *t, *u, *bw0, *bb0, *bw1, *bb1, *bw2, *bb2, *bw3, *bb3, *bw4, *bb4, *W1, *W2;
    float* out;
    u16 *ubf, *bw0t, *bw1t, *bw2t, *bw3t, *BWt, *z, *h1, *h2, *Bt, *actA, *actB;
    float *bz, *zc, *Cp;
};

// ---------------------------------------------------------------------------
// Branch GEMM stage: 64(M)x128(N) tile, 256 tiles, 8 waves (2M x 4N), BK=32.
// C = tanh(A @ Bt^T + bias), bf16 out, ldc = 1024.
// ---------------------------------------------------------------------------
__device__ __forceinline__ void branch_stage(char* lds,
        const u16* __restrict__ A, int lda,
        const u16* __restrict__ Bt, int ldb,
        const float* __restrict__ bias,
        u16* __restrict__ C, int K, int bid, int tid)
{
    u16 (*As)[64 * 32] = (u16(*)[64 * 32])lds;            // 2 x 4 KB
    u16 (*Bs)[128 * 32] = (u16(*)[128 * 32])(lds + 8192); // 2 x 8 KB
    const int lane = tid & 63, wid = tid >> 6;
    const int wr = wid >> 2, wc = wid & 3;
    const int bn = (bid & 7) * 128, bm = (bid >> 3) * 64;
    const int NT = K >> 5;
    const int ck = tid & 3;
    const int arow = (tid & 255) >> 2;
    const int brow = tid >> 2;
    const u16* aSrc = A + (size_t)(bm + arow) * lda + (ck ^ (arow & 3)) * 8;
    const u16* bSrc = Bt + (size_t)(bn + brow) * ldb + (ck ^ (brow & 3)) * 8;
    f32x4 acc[2][2] = {};

    auto STAGE = [&](int buf, int t) {
        const int k0 = t << 5;
        if (tid < 256) gload_lds16(aSrc + k0, (char*)As[buf] + wid * 1024);
        gload_lds16(bSrc + k0, (char*)Bs[buf] + wid * 1024);
    };
    auto COMPUTE = [&](int buf) {
        s16x8 av[2], bv[2];
        #pragma unroll
        for (int mi = 0; mi < 2; ++mi) {
            int row = wr * 32 + mi * 16 + (lane & 15);
            int s = (lane >> 4) ^ (row & 3);
            av[mi] = *(const s16x8*)&As[buf][row * 32 + s * 8];
        }
        #pragma unroll
        for (int ni = 0; ni < 2; ++ni) {
            int col = wc * 32 + ni * 16 + (lane & 15);
            int s = (lane >> 4) ^ (col & 3);
            bv[ni] = *(const s16x8*)&Bs[buf][col * 32 + s * 8];
        }
        #pragma unroll
        for (int mi = 0; mi < 2; ++mi)
        #pragma unroll
        for (int ni = 0; ni < 2; ++ni)
            acc[mi][ni] = MFMA(av[mi], bv[ni], acc[mi][ni]);
    };

    STAGE(0, 0);
    __syncthreads();
    for (int t = 0; t < NT; ++t) {
        if (t + 1 < NT) STAGE((t + 1) & 1, t + 1);
        COMPUTE(t & 1);
        __syncthreads();
    }
    #pragma unroll
    for (int mi = 0; mi < 2; ++mi)
    #pragma unroll
    for (int ni = 0; ni < 2; ++ni) {
        const int col = bn + wc * 32 + ni * 16 + (lane & 15);
        const float bvs = bias[col];
        #pragma unroll
        for (int jj = 0; jj < 4; ++jj) {
            const int row = bm + wr * 32 + mi * 16 + (lane >> 4) * 4 + jj;
            C[(size_t)row * 1024 + col] = f2bf(fast_tanh(acc[mi][ni][jj] + bvs));
        }
    }
}

// ---------------------------------------------------------------------------
// z-GEMM stage: zc[kz][2048][64] partials = actB @ BWt^T, 32 M-tiles x 8 kz.
// 8 waves (4M x 2N), wave 16x32, frags 1x2.
// ---------------------------------------------------------------------------
__device__ __forceinline__ void z_stage(char* lds, const u16* __restrict__ actB,
        const u16* __restrict__ BWt, float* __restrict__ zc, int bid, int tid)
{
    u16 (*As)[64 * 32] = (u16(*)[64 * 32])lds;
    u16 (*Bs)[64 * 32] = (u16(*)[64 * 32])(lds + 8192);
    const int lane = tid & 63, wid = tid >> 6;
    const int wr = wid >> 1, wc = wid & 1;
    const int bm = (bid >> 3) * 64, kz = bid & 7;
    const int t0 = kz * 4;
    const int ck = tid & 3;
    const int arow = (tid & 255) >> 2;
    const u16* aSrc = actB + (size_t)(bm + arow) * 1024 + (ck ^ (arow & 3)) * 8;
    const u16* bSrc = BWt + (size_t)arow * 1024 + (ck ^ (arow & 3)) * 8;
    f32x4 acc[2] = {};

    auto STAGE = [&](int buf, int t) {
        const int k0 = t << 5;
        if (tid < 256) gload_lds16(aSrc + k0, (char*)As[buf] + wid * 1024);
        else           gload_lds16(bSrc + k0, (char*)Bs[buf] + (wid - 4) * 1024);
    };
    auto COMPUTE = [&](int buf) {
        int row = wr * 16 + (lane & 15);
        int sa = (lane >> 4) ^ (row & 3);
        s16x8 av = *(const s16x8*)&As[buf][row * 32 + sa * 8];
        #pragma unroll
        for (int ni = 0; ni < 2; ++ni) {
            int col = wc * 32 + ni * 16 + (lane & 15);
            int sb = (lane >> 4) ^ (col & 3);
            s16x8 bv = *(const s16x8*)&Bs[buf][col * 32 + sb * 8];
            acc[ni] = MFMA(av, bv, acc[ni]);
        }
    };

    STAGE(0, t0);
    __syncthreads();
    for (int t = 0; t < 4; ++t) {
        if (t + 1 < 4) STAGE((t + 1) & 1, t0 + t + 1);
        COMPUTE(t & 1);
        __syncthreads();
    }
    #pragma unroll
    for (int ni = 0; ni < 2; ++ni) {
        int col = wc * 32 + ni * 16 + (lane & 15);
        #pragma unroll
        for (int jj = 0; jj < 4; ++jj) {
            int row = bm + wr * 16 + (lane >> 4) * 4 + jj;
            zc[((size_t)kz * 2048 + row) * 64 + col] = acc[ni][jj];
        }
    }
}

// ---------------------------------------------------------------------------
// Trunk GEMM stage: 128x128 tile, 16 M x 16 kz, 8 waves (4M x 2N), K=8256.
// A generated on the fly: p<8192: h[b,p>>6]*z[b,p&63]; else z[b,p-8192].
// ---------------------------------------------------------------------------
__device__ __forceinline__ void trunk_stage(char* lds, const u16* __restrict__ h,
        const u16* __restrict__ z, const u16* __restrict__ Bt,
        float* __restrict__ Cp, int bid, int tid)
{
    constexpr int NT = 258, SKT = 16;
    u16 (*As)[128 * 32] = (u16(*)[128 * 32])lds;              // 2 x 8 KB
    u16 (*Bs)[128 * 32] = (u16(*)[128 * 32])(lds + 16384);    // 2 x 8 KB
    const int lane = tid & 63, wid = tid >> 6;
    const int wr = wid >> 1, wc = wid & 1;
    const int bm = (bid >> 4) * 128, kz = bid & 15;
    const int t0 = (NT * kz) / SKT, t1 = (NT * (kz + 1)) / SKT;
    const int arow = tid >> 2, ck = tid & 3;
    const int b = bm + arow;
    const s16x8 zlo = *(const s16x8*)&z[b * 64 + ck * 8];
    const s16x8 zhi = *(const s16x8*)&z[b * 64 + 32 + ck * 8];
    const int slot = (ck ^ (arow & 3)) * 8;
    f32x4 acc[2][4] = {};

    auto STAGE = [&](int buf, int t) {
        const int p0 = t << 5;
        gload_lds16(Bt + (size_t)arow * 8256 + p0 + (ck ^ (arow & 3)) * 8,
                    (char*)Bs[buf] + wid * 1024);
        const s16x8 zv = (p0 & 32) ? zhi : zlo;
        u16 o8[8];
        if (p0 < 8192) {
            const float hf = bf2f(h[b * 128 + (p0 >> 6)]);
            #pragma unroll
            for (int j = 0; j < 8; ++j) o8[j] = f2bf(hf * bf2f((u16)zv[j]));
        } else {
            #pragma unroll
            for (int j = 0; j < 8; ++j) o8[j] = (u16)zv[j];
        }
        *(s16x8*)&As[buf][arow * 32 + slot] = *(s16x8*)o8;
    };
    auto COMPUTE = [&](int buf) {
        s16x8 av[2], bb[4];
        #pragma unroll
        for (int mi = 0; mi < 2; ++mi) {
            int row = wr * 32 + mi * 16 + (lane & 15);
            int s = (lane >> 4) ^ (row & 3);
            av[mi] = *(const s16x8*)&As[buf][row * 32 + s * 8];
        }
        #pragma unroll
        for (int ni = 0; ni < 4; ++ni) {
            int n = wc * 64 + ni * 16 + (lane & 15);
            int s = (lane >> 4) ^ (n & 3);
            bb[ni] = *(const s16x8*)&Bs[buf][n * 32 + s * 8];
        }
        #pragma unroll
        for (int mi = 0; mi < 2; ++mi)
        #pragma unroll
        for (int ni = 0; ni < 4; ++ni)
            acc[mi][ni] = MFMA(av[mi], bb[ni], acc[mi][ni]);
    };

    STAGE(0, t0);
    __syncthreads();
    const int nt = t1 - t0;
    for (int t = 0; t < nt; ++t) {
        if (t + 1 < nt) STAGE((t + 1) & 1, t0 + t + 1);
        COMPUTE(t & 1);
        __syncthreads();
    }
    #pragma unroll
    for (int mi = 0; mi < 2; ++mi)
    #pragma unroll
    for (int ni = 0; ni < 4; ++ni) {
        const int col = wc * 64 + ni * 16 + (lane & 15);
        #pragma unroll
        for (int jj = 0; jj < 4; ++jj) {
            const int row = bm + wr * 32 + mi * 16 + (lane >> 4) * 4 + jj;
            Cp[((size_t)kz * 2048 + row) * 128 + col] = acc[mi][ni][jj];
        }
    }
}

// ---------------------------------------------------------------------------
// THE mega-kernel: whole pipeline, grid 256 x 512, 10 grid syncs.
// ---------------------------------------------------------------------------
__global__ __launch_bounds__(512, 2)
void mega(Args a)
{
    __shared__ __align__(16) char lds[32768];
    cg::grid_group grid = cg::this_grid();
    const int bid = blockIdx.x, tid = threadIdx.x;

    // ============== STAGE P: all prep, 1893 block-units ==============
    for (int unit = bid; unit < 1893; unit += 256) {
        __syncthreads();
        if (unit < 64) {                       // u -> ubf
            int i = (unit * 512 + tid) * 8;
            float4 x = *(const float4*)&a.u[i];
            float4 y = *(const float4*)&a.u[i + 4];
            uint4 o;
            o.x = (u32)f2bf(x.x) | ((u32)f2bf(x.y) << 16);
            o.y = (u32)f2bf(x.z) | ((u32)f2bf(x.w) << 16);
            o.z = (u32)f2bf(y.x) | ((u32)f2bf(y.y) << 16);
            o.w = (u32)f2bf(y.z) | ((u32)f2bf(y.w) << 16);
            *(uint4*)&a.ubf[i] = o;
        } else if (unit < 864) {               // weight transposes
            float (*tile)[65] = (float(*)[65])lds;
            const float* src; u16* dst; int lddst, rb, cb;
            if (unit < 96) {
                int idx = unit - 64;
                src = a.bw0; dst = a.bw0t; lddst = 128;
                rb = (idx >> 4) * 64; cb = (idx & 15) * 64;
            } else {
                int idx = unit - 96;
                int ly = idx >> 8, w = idx & 255;
                src = ly == 0 ? a.bw1 : (ly == 1 ? a.bw2 : a.bw3);
                dst = ly == 0 ? a.bw1t : (ly == 1 ? a.bw2t : a.bw3t);
                lddst = 1024;
                rb = (w >> 4) * 64; cb = (w & 15) * 64;
            }
            for (int i = tid; i < 4096; i += 512) {
                int r = i >> 6, c = i & 63;
                tile[r][c] = src[(size_t)(rb + r) * 1024 + cb + c];
            }
            __syncthreads();
            for (int i = tid; i < 4096; i += 512) {
                int c = i >> 6, r = i & 63;
                dst[(size_t)(cb + c) * lddst + rb + r] = f2bf(tile[r][c]);
            }
        } else if (unit < 1376) {              // BWt = (bw4@W1)^T, f32-parallel
            float (*sh)[2][64] = (float(*)[2][64])lds;   // [8][2][64]
            const int k0 = (unit - 864) * 2;
            const int n = tid & 63, jc = tid >> 6;
            float a0 = 0.f, a1 = 0.f;
            for (int j = jc * 128; j < jc * 128 + 128; ++j) {
                float w = a.W1[j * 64 + n];
                a0 = fmaf(a.bw4[(size_t)k0 * 1024 + j], w, a0);
                a1 = fmaf(a.bw4[(size_t)(k0 + 1) * 1024 + j], w, a1);
            }
            sh[jc][0][n] = a0; sh[jc][1][n] = a1;
            __syncthreads();
            if (tid < 128) {
                int kk = tid >> 6, nn = tid & 63;
                float s = 0.f;
                #pragma unroll
                for (int q = 0; q < 8; ++q) s += sh[q][kk][nn];
                a.BWt[(size_t)nn * 1024 + k0 + kk] = f2bf(s);
            }
        } else if (unit == 1376) {             // bz = bb4 @ W1
            float (*sh1)[64] = (float(*)[64])lds;
            const int n = tid & 63, jc = tid >> 6;
            float s = 0.f;
            for (int j = jc * 128; j < jc * 128 + 128; ++j)
                s = fmaf(a.bb4[j], a.W1[j * 64 + n], s);
            sh1[jc][n] = s;
            __syncthreads();
            if (tid < 64) {
                float v = 0.f;
                #pragma unroll
                for (int q = 0; q < 8; ++q) v += sh1[q][tid];
                a.bz[tid] = v;
            }
        } else {                               // gather trunk weights
            float (*tile)[130] = (float(*)[130])lds;     // [32][130]
            const int idx = unit - 1377;
            const int ly = idx / 258, pbi = idx % 258;
            u16* Btd = a.Bt + (size_t)ly * 128 * 8256;
            const int colbase = ly ? 16896 : 384, biasbase = ly ? 16768 : 256;
            const int pb = pbi * 32;
            for (int i = tid; i < 4096; i += 512) {
                int p = pb + (i >> 7), n = i & 127;
                float v = (p < 8192)
                    ? a.W2[(size_t)(p & 63) * LDP + colbase + (size_t)(p >> 6) * 128 + n]
                    : a.W2[(size_t)(p - 8192) * LDP + biasbase + n];
                tile[i >> 7][n] = v;
            }
            __syncthreads();
            for (int i = tid; i < 4096; i += 512) {
                int n = i >> 5, dp = i & 31;
                Btd[(size_t)n * 8256 + pb + dp] = f2bf(tile[dp][n]);
            }
        }
    }
    grid.sync();

    // ============== branch MLP (bw4@W1 folded into BWt) ==============
    branch_stage(lds, a.ubf, 128, a.bw0t, 128, a.bb0, a.actA, 128, bid, tid);
    grid.sync();
    branch_stage(lds, a.actA, 1024, a.bw1t, 1024, a.bb1, a.actB, 1024, bid, tid);
    grid.sync();
    branch_stage(lds, a.actB, 1024, a.bw2t, 1024, a.bb2, a.actA, 1024, bid, tid);
    grid.sync();
    branch_stage(lds, a.actA, 1024, a.bw3t, 1024, a.bb3, a.actB, 1024, bid, tid);
    grid.sync();

    // ============== z partials ==============
    z_stage(lds, a.actB, a.BWt, a.zc, bid, tid);
    grid.sync();

    // ============== reduce z + trunk L1 + h1 ==============
    {
        float (*zsh)[64] = (float(*)[64])lds;   // [8][64]
        const int rb = bid * 8;
        {
            int r = tid >> 6, k = tid & 63;
            size_t off = (size_t)(rb + r) * 64 + k;
            float s = a.bz[k];
            #pragma unroll
            for (int sk = 0; sk < 8; ++sk) s += a.zc[(size_t)sk * 2048 * 64 + off];
            zsh[r][k] = s;
            a.z[off] = f2bf(s);
        }
        __syncthreads();
        const int o = tid & 127;
        const int rg = (tid >> 7) * 2;
        float aa[2] = {}, ab[2] = {};
        for (int k = 0; k < 64; ++k) {
            float wa = a.W2[(size_t)k * LDP + o];
            float wb = a.W2[(size_t)k * LDP + 128 + o];
            #pragma unroll
            for (int rr = 0; rr < 2; ++rr) {
                float zv = zsh[rg + rr][k];
                aa[rr] = fmaf(zv, wa, aa[rr]);
                ab[rr] = fmaf(zv, wb, ab[rr]);
            }
        }
        #pragma unroll
        for (int rr = 0; rr < 2; ++rr) {
            int b = rb + rg + rr;
            a.h1[b * 128 + o] = f2bf(fast_tanh(a.t[b] * ab[rr] + aa[rr]));
        }
    }
    grid.sync();

    // ============== trunk layer 2 ==============
    trunk_stage(lds, a.h1, a.z, a.Bt, a.Cp, bid, tid);
    grid.sync();

    // ============== reduce + tanh -> h2 ==============
    {
        const size_t S = (size_t)2048 * 128;
        #pragma unroll
        for (int q = 0; q < 2; ++q) {
            int e = bid * 1024 + q * 512 + tid;
            float s = 0.f;
            #pragma unroll
            for (int k = 0; k < 16; ++k) s += a.Cp[e + k * S];
            a.h2[e] = f2bf(fast_tanh(s));
        }
    }
    grid.sync();

    // ============== trunk layer 3 ==============
    trunk_stage(lds, a.h2, a.z, a.Bt + (size_t)128 * 8256, a.Cp, bid, tid);
    grid.sync();

    // ============== layer-3 reduce + trunk L4 + combine ==============
    {
        float (*sh)[128] = (float(*)[128])lds;   // [8][128]
        const int wv = tid >> 6, l = tid & 63;
        const int b = bid * 8 + wv;
        const size_t S = (size_t)2048 * 128;
        #pragma unroll
        for (int e = l; e < 128; e += 64) {
            float s = 0.f;
            #pragma unroll
            for (int k = 0; k < 16; ++k) s += a.Cp[k * S + (size_t)b * 128 + e];
            sh[wv][e] = fast_tanh(s);
        }
        __syncthreads();
        const float* wrow = &a.W2[(size_t)l * LDP + 33280];
        float acc = wrow[0];
        #pragma unroll 8
        for (int i = 0; i < 128; ++i) acc = fmaf(sh[wv][i], wrow[1 + i], acc);
        float p = bf2f(a.z[b * 64 + l]) * acc;
        #pragma unroll
        for (int off = 32; off > 0; off >>= 1) p += __shfl_down(p, off);
        if (l == 0) a.out[b] = a.u[b * 128] + a.t[b] * p;
    }
}

// ---------------------------------------------------------------------------
extern "C" void kernel_launch(void* const* d_in, const int* in_sizes, int n_in,
                              void* d_out, int out_size, void* d_ws, size_t ws_size,
                              hipStream_t stream)
{
    char* base = (char*)d_ws;
    Args a;
    a.t   = (const float*)d_in[0];
    a.u   = (const float*)d_in[1];
    a.bw0 = (const float*)d_in[2];
    a.bb0 = (const float*)d_in[3];
    a.bw1 = (const float*)d_in[4];
    a.bb1 = (const float*)d_in[5];
    a.bw2 = (const float*)d_in[6];
    a.bb2 = (const float*)d_in[7];
    a.bw3 = (const float*)d_in[8];
    a.bb3 = (const float*)d_in[9];
    a.bw4 = (const float*)d_in[10];
    a.bb4 = (const float*)d_in[11];
    a.W1  = (const float*)d_in[12];
    a.W2  = (const float*)d_in[13];
    a.out = (float*)d_out;
    // workspace layout (bytes) — same as r9
    a.bw1t = (u16*)(base);                  // 2 MB
    a.bw2t = (u16*)(base + 2097152);        // 2 MB
    a.bw3t = (u16*)(base + 4194304);        // 2 MB
    a.actA = (u16*)(base + 6291456);        // 4 MB
    a.actB = (u16*)(base + 10485760);       // 4 MB
    a.ubf  = (u16*)(base + 14680064);       // 512 KB
    a.bw0t = (u16*)(base + 15204352);       // 256 KB
    a.BWt  = (u16*)(base + 15499264);       // 128 KB
    a.bz   = (float*)(base + 15630336);     // 256 B
    a.z    = (u16*)(base + 16777216);       // 256 KB
    a.h1   = (u16*)(base + 17039360);       // 512 KB
    a.h2   = (u16*)(base + 17563648);       // 512 KB
    a.Bt   = (u16*)(base + 18087936);       // 4,227,072 (2 layers)
    // overlays (liveness crosses grid syncs):
    a.zc   = (float*)(base);                // 4 MB   (Z .. ZL1; over bw1t/bw2t, dead)
    a.Cp   = (float*)(base);                // 16 MB  (T2..OUT; over all prep/act, dead)

    void* params[] = { (void*)&a };
    hipLaunchCooperativeKernel((void*)mega, dim3(256), dim3(512), params, 0, stream);
}

// Round 11
// 137.932 us; speedup vs baseline: 3.3792x; 3.3792x over previous
//
#include <hip/hip_runtime.h>
#include <hip/hip_bf16.h>
#include <stdint.h>

typedef unsigned short u16;
typedef unsigned int   u32;
typedef short s16x8 __attribute__((ext_vector_type(8)));
typedef float f32x4 __attribute__((ext_vector_type(4)));

#define LDP 33409

__device__ __forceinline__ u16 f2bf(float f) {
    union { float f; u32 u; } v; v.f = f;
    u32 r = v.u + 0x7fffu + ((v.u >> 16) & 1u);
    return (u16)(r >> 16);
}
__device__ __forceinline__ float bf2f(u16 h) {
    union { u32 u; float f; } v; v.u = ((u32)h) << 16;
    return v.f;
}
__device__ __forceinline__ float fast_tanh(float x) {
    float e = __expf(2.0f * x);
    return 1.0f - 2.0f / (e + 1.0f);
}
__device__ __forceinline__ f32x4 MFMA(s16x8 a, s16x8 b, f32x4 c) {
    return __builtin_amdgcn_mfma_f32_16x16x32_bf16(a, b, c, 0, 0, 0);
}
__device__ __forceinline__ void gload_lds16(const void* g, void* l) {
    __builtin_amdgcn_global_load_lds(
        (const __attribute__((address_space(1))) u32*)(uintptr_t)g,
        (__attribute__((address_space(3))) u32*)(uintptr_t)l, 16, 0, 0);
}

// ---------------------------------------------------------------------------
// prep0: [0,128) cvt u -> ubf ; [128,160) transpose bw0 -> bw0t[1024][128]
// ---------------------------------------------------------------------------
__global__ __launch_bounds__(256)
void prep0(const float* __restrict__ u, const float* __restrict__ bw0,
           u16* __restrict__ ubf, u16* __restrict__ bw0t)
{
    __shared__ float tile[64][65];
    const int bid = blockIdx.x, tid = threadIdx.x;
    if (bid < 128) {
        int i = (bid * 256 + tid) * 8;
        float4 a = *(const float4*)&u[i];
        float4 b = *(const float4*)&u[i + 4];
        uint4 o;
        o.x = (u32)f2bf(a.x) | ((u32)f2bf(a.y) << 16);
        o.y = (u32)f2bf(a.z) | ((u32)f2bf(a.w) << 16);
        o.z = (u32)f2bf(b.x) | ((u32)f2bf(b.y) << 16);
        o.w = (u32)f2bf(b.z) | ((u32)f2bf(b.w) << 16);
        *(uint4*)&ubf[i] = o;
        return;
    }
    const int idx = bid - 128;
    const int rb = (idx >> 4) * 64, cb = (idx & 15) * 64;
    for (int i = tid; i < 64 * 64; i += 256) {
        int r = i >> 6, c = i & 63;
        tile[r][c] = bw0[(size_t)(rb + r) * 1024 + cb + c];
    }
    __syncthreads();
    for (int i = tid; i < 64 * 64; i += 256) {
        int c = i >> 6, r = i & 63;
        bw0t[(size_t)(cb + c) * 128 + rb + r] = f2bf(tile[r][c]);
    }
}

// ---------------------------------------------------------------------------
// Fused branch GEMM + horizontal prep.
// blocks [0,256): 128(M)x64(N) GEMM  C = tanh(A @ Bt^T + bias)
//                 bn=(b&15)*64, bm=(b>>4)*128; 4 waves (2Mx2N), BK=32.
// mode 0/1/2, blocks [256,512): transpose xsrc(1024^2) -> xdst[n][k]
// mode 2, blocks [512,1025):    BWt[n][k]=(bw4@W1)[k][n]; block 1024: bz
// mode 3, blocks [256,772):     gather trunk Bt[layer][n][p] (32-row tiles)
// ---------------------------------------------------------------------------
__global__ __launch_bounds__(256, 2)
void gemm_fused(const u16* __restrict__ A, int lda,
                const u16* __restrict__ Bt, int ldb,
                const float* __restrict__ bias,
                u16* __restrict__ Cout, int ldc, int K, int mode,
                const float* __restrict__ xsrc, u16* __restrict__ xdst,
                const float* __restrict__ bw4, const float* __restrict__ bb4,
                const float* __restrict__ W1, u16* __restrict__ BWt,
                float* __restrict__ bz,
                const float* __restrict__ W2, u16* __restrict__ Btb)
{
    __shared__ __align__(16) char lds[24576];
    const int bid = blockIdx.x, tid = threadIdx.x;

    if (bid < 256) {                           // ================= GEMM 128x64
        u16 (*As)[128 * 32] = (u16(*)[128 * 32])lds;          // 2 x 8 KB
        u16 (*Bs)[64 * 32]  = (u16(*)[64 * 32])(lds + 16384); // 2 x 4 KB
        const int lane = tid & 63, wid = tid >> 6;
        const int wr = wid >> 1, wc = wid & 1;
        const int bn = (bid & 15) * 64, bm = (bid >> 4) * 128;
        const int NT = K >> 5;
        const int arow = tid >> 2, ck = tid & 3;
        const u16* aSrc = A + (size_t)(bm + arow) * lda + (ck ^ (arow & 3)) * 8;
        const u16* bSrc = Bt + (size_t)(bn + arow) * ldb + (ck ^ (arow & 3)) * 8;
        const size_t aHalf = (size_t)64 * lda;   // rows +64 (64%4==0: same swizzle)
        f32x4 acc[4][2] = {};

        auto STAGE = [&](int buf, int t) {
            const int k0 = t << 5;
            gload_lds16(aSrc + k0,         (char*)As[buf] + wid * 1024);
            gload_lds16(aSrc + aHalf + k0, (char*)As[buf] + 4096 + wid * 1024);
            gload_lds16(bSrc + k0,         (char*)Bs[buf] + wid * 1024);
        };
        auto COMPUTE = [&](int buf) {
            s16x8 av[4], bv[2];
            #pragma unroll
            for (int mi = 0; mi < 4; ++mi) {
                int row = wr * 64 + mi * 16 + (lane & 15);
                int s = (lane >> 4) ^ (row & 3);
                av[mi] = *(const s16x8*)&As[buf][row * 32 + s * 8];
            }
            #pragma unroll
            for (int ni = 0; ni < 2; ++ni) {
                int col = wc * 32 + ni * 16 + (lane & 15);
                int s = (lane >> 4) ^ (col & 3);
                bv[ni] = *(const s16x8*)&Bs[buf][col * 32 + s * 8];
            }
            #pragma unroll
            for (int mi = 0; mi < 4; ++mi)
            #pragma unroll
            for (int ni = 0; ni < 2; ++ni)
                acc[mi][ni] = MFMA(av[mi], bv[ni], acc[mi][ni]);
        };

        STAGE(0, 0);
        __syncthreads();
        for (int t = 0; t < NT; ++t) {
            if (t + 1 < NT) STAGE((t + 1) & 1, t + 1);
            COMPUTE(t & 1);
            __syncthreads();
        }
        #pragma unroll
        for (int mi = 0; mi < 4; ++mi)
        #pragma unroll
        for (int ni = 0; ni < 2; ++ni) {
            const int col = bn + wc * 32 + ni * 16 + (lane & 15);
            const float bv = bias[col];
            #pragma unroll
            for (int jj = 0; jj < 4; ++jj) {
                const int row = bm + wr * 64 + mi * 16 + (lane >> 4) * 4 + jj;
                Cout[(size_t)row * ldc + col] = f2bf(fast_tanh(acc[mi][ni][jj] + bv));
            }
        }
    } else if (mode <= 2 && bid < 512) {       // ================= transpose 1024^2
        float (*tile)[65] = (float(*)[65])lds;
        const int idx = bid - 256;
        const int rb = (idx >> 4) * 64, cb = (idx & 15) * 64;
        for (int i = tid; i < 64 * 64; i += 256) {
            int r = i >> 6, c = i & 63;
            tile[r][c] = xsrc[(size_t)(rb + r) * 1024 + cb + c];
        }
        __syncthreads();
        for (int i = tid; i < 64 * 64; i += 256) {
            int c = i >> 6, r = i & 63;
            xdst[(size_t)(cb + c) * 1024 + rb + r] = f2bf(tile[r][c]);
        }
    } else if (mode == 2) {                    // ================= BW / bz
        const int lb = bid - 512;              // 0..512
        const int n = tid & 63, jc = tid >> 6;
        if (lb == 512) {
            float (*sh1)[64] = (float(*)[64])lds;
            float a = 0.f;
            for (int j = jc * 256; j < jc * 256 + 256; ++j)
                a = fmaf(bb4[j], W1[j * 64 + n], a);
            sh1[jc][n] = a;
            __syncthreads();
            if (tid < 64)
                bz[tid] = sh1[0][tid] + sh1[1][tid] + sh1[2][tid] + sh1[3][tid];
            return;
        }
        float (*sh)[2][64] = (float(*)[2][64])lds;     // [4][2][64]
        const int k0 = lb * 2;
        float a0 = 0.f, a1 = 0.f;
        for (int j = jc * 256; j < jc * 256 + 256; ++j) {
            float w = W1[j * 64 + n];
            a0 = fmaf(bw4[(size_t)k0 * 1024 + j], w, a0);
            a1 = fmaf(bw4[(size_t)(k0 + 1) * 1024 + j], w, a1);
        }
        sh[jc][0][n] = a0; sh[jc][1][n] = a1;
        __syncthreads();
        if (tid < 128) {
            int kk = tid >> 6, nn = tid & 63;
            float s = sh[0][kk][nn] + sh[1][kk][nn] + sh[2][kk][nn] + sh[3][kk][nn];
            BWt[(size_t)nn * 1024 + k0 + kk] = f2bf(s);
        }
    } else {                                   // ================= gather trunk (mode 3)
        float (*tile)[130] = (float(*)[130])lds;       // [32][130] = 16.6 KB
        const int idx = bid - 256;             // 0..515
        const int layer = idx / 258, pbi = idx % 258;
        u16* Btd = Btb + (size_t)layer * 128 * 8256;
        const int colbase = layer ? 16896 : 384, biasbase = layer ? 16768 : 256;
        const int pb = pbi * 32;
        for (int i = tid; i < 32 * 128; i += 256) {
            int p = pb + (i >> 7), n = i & 127;
            float v = (p < 8192)
                ? W2[(size_t)(p & 63) * LDP + colbase + (size_t)(p >> 6) * 128 + n]
                : W2[(size_t)(p - 8192) * LDP + biasbase + n];
            tile[i >> 7][n] = v;
        }
        __syncthreads();
        for (int i = tid; i < 32 * 128; i += 256) {
            int n = i >> 5, dp = i & 31;
            Btd[(size_t)n * 8256 + pb + dp] = f2bf(tile[dp][n]);
        }
    }
}

// ---------------------------------------------------------------------------
// z-GEMM: zc[kz][2048][64] = actB @ BWt^T partials, SK=8, 64x64 tile
// ---------------------------------------------------------------------------
__global__ __launch_bounds__(256, 2)
void zgemm(const u16* __restrict__ A, const u16* __restrict__ Bt,
           float* __restrict__ zc)
{
    __shared__ __align__(16) u16 As[2][64 * 32];
    __shared__ __align__(16) u16 Bs[2][64 * 32];
    const int tid = threadIdx.x, lane = tid & 63, wid = tid >> 6;
    const int wr = wid >> 1, wc = wid & 1;
    const int bm = blockIdx.y * 64, kz = blockIdx.z;
    const int t0 = kz * 4, nt = 4;
    const int arow = tid >> 2, ck = tid & 3;
    const u16* aSrc = A + (size_t)(bm + arow) * 1024 + (ck ^ (arow & 3)) * 8;
    const u16* bSrc = Bt + (size_t)arow * 1024 + (ck ^ (arow & 3)) * 8;
    f32x4 acc[2][2] = {};

    auto STAGE = [&](int buf, int t) {
        const int k0 = t << 5;
        gload_lds16(aSrc + k0, (char*)As[buf] + wid * 1024);
        gload_lds16(bSrc + k0, (char*)Bs[buf] + wid * 1024);
    };
    auto COMPUTE = [&](int buf) {
        s16x8 a[2];
        #pragma unroll
        for (int mi = 0; mi < 2; ++mi) {
            int row = wr * 32 + mi * 16 + (lane & 15);
            int s = (lane >> 4) ^ (row & 3);
            a[mi] = *(const s16x8*)&As[buf][row * 32 + s * 8];
        }
        #pragma unroll
        for (int ni = 0; ni < 2; ++ni) {
            int n = wc * 32 + ni * 16 + (lane & 15);
            int s = (lane >> 4) ^ (n & 3);
            s16x8 b = *(const s16x8*)&Bs[buf][n * 32 + s * 8];
            #pragma unroll
            for (int mi = 0; mi < 2; ++mi)
                acc[mi][ni] = MFMA(a[mi], b, acc[mi][ni]);
        }
    };

    STAGE(0, t0);
    __syncthreads();
    for (int t = 0; t < nt; ++t) {
        if (t + 1 < nt) STAGE((t + 1) & 1, t0 + t + 1);
        COMPUTE(t & 1);
        __syncthreads();
    }
    #pragma unroll
    for (int mi = 0; mi < 2; ++mi)
    #pragma unroll
    for (int ni = 0; ni < 2; ++ni) {
        const int col = wc * 32 + ni * 16 + (lane & 15);
        #pragma unroll
        for (int jj = 0; jj < 4; ++jj) {
            const int row = bm + wr * 32 + mi * 16 + (lane >> 4) * 4 + jj;
            zc[((size_t)kz * 2048 + row) * 64 + col] = acc[mi][ni][jj];
        }
    }
}

// ---------------------------------------------------------------------------
// Fused: reduce_z (+bz) -> z bf16 ; trunk L1 (K=64, VALU) -> h1 bf16
// ---------------------------------------------------------------------------
__global__ __launch_bounds__(256)
void z_l1_h1(const float* __restrict__ zc, const float* __restrict__ bz,
             const float* __restrict__ W2, const float* __restrict__ t,
             u16* __restrict__ z, u16* __restrict__ h1)
{
    __shared__ float zsh[16][64];
    const int rb = blockIdx.x * 16;
    #pragma unroll
    for (int ii = 0; ii < 4; ++ii) {
        int e = ii * 256 + threadIdx.x;
        int r = e >> 6, k = e & 63;
        size_t off = (size_t)(rb + r) * 64 + k;
        float s = bz[k];
        #pragma unroll
        for (int sk = 0; sk < 8; ++sk) s += zc[(size_t)sk * 2048 * 64 + off];
        zsh[r][k] = s;
        z[off] = f2bf(s);
    }
    __syncthreads();
    const int o = threadIdx.x & 127;
    const int rh = (threadIdx.x >> 7) * 8;
    float acc_a[8] = {}, acc_b[8] = {};
    for (int k = 0; k < 64; ++k) {
        float wa = W2[(size_t)k * LDP + o];
        float wb = W2[(size_t)k * LDP + 128 + o];
        #pragma unroll
        for (int r = 0; r < 8; ++r) {
            float zv = zsh[rh + r][k];
            acc_a[r] = fmaf(zv, wa, acc_a[r]);
            acc_b[r] = fmaf(zv, wb, acc_b[r]);
        }
    }
    #pragma unroll
    for (int r = 0; r < 8; ++r) {
        int b = rb + rh + r;
        h1[b * 128 + o] = f2bf(fast_tanh(t[b] * acc_b[r] + acc_a[r]));
    }
}

// ---------------------------------------------------------------------------
// Trunk GEMM: 512 threads / 8 waves (4Mx2N), 128x128 tile, SK=16.
// A generated on the fly: p<8192: h[b,p>>6]*z[b,p&63]; else z[b,p-8192].
// ---------------------------------------------------------------------------
__global__ __launch_bounds__(512, 2)
void trunk128(const u16* __restrict__ h, const u16* __restrict__ z,
              const u16* __restrict__ Bt, float* __restrict__ Cp)
{
    constexpr int NT = 258, SKT = 16;
    __shared__ __align__(16) u16 As[2][128 * 32];
    __shared__ __align__(16) u16 Bs[2][128 * 32];
    const int tid = threadIdx.x, lane = tid & 63, wid = tid >> 6;
    const int wr = wid >> 1, wc = wid & 1;
    const int bm = blockIdx.x * 128, kz = blockIdx.y;
    const int t0 = (NT * kz) / SKT, t1 = (NT * (kz + 1)) / SKT;
    const int arow = tid >> 2, ck = tid & 3;
    const int b = bm + arow;
    const s16x8 zlo = *(const s16x8*)&z[b * 64 + ck * 8];
    const s16x8 zhi = *(const s16x8*)&z[b * 64 + 32 + ck * 8];
    const int slot = (ck ^ (arow & 3)) * 8;
    f32x4 acc[2][4] = {};

    auto STAGE = [&](int buf, int t) {
        const int p0 = t << 5;
        gload_lds16(Bt + (size_t)arow * 8256 + p0 + (ck ^ (arow & 3)) * 8,
                    (char*)Bs[buf] + wid * 1024);
        const s16x8 zv = (p0 & 32) ? zhi : zlo;
        u16 o8[8];
        if (p0 < 8192) {
            const float hf = bf2f(h[b * 128 + (p0 >> 6)]);
            #pragma unroll
            for (int j = 0; j < 8; ++j) o8[j] = f2bf(hf * bf2f((u16)zv[j]));
        } else {
            #pragma unroll
            for (int j = 0; j < 8; ++j) o8[j] = (u16)zv[j];
        }
        *(s16x8*)&As[buf][arow * 32 + slot] = *(s16x8*)o8;
    };
    auto COMPUTE = [&](int buf) {
        s16x8 av[2], bb[4];
        #pragma unroll
        for (int mi = 0; mi < 2; ++mi) {
            int row = wr * 32 + mi * 16 + (lane & 15);
            int s = (lane >> 4) ^ (row & 3);
            av[mi] = *(const s16x8*)&As[buf][row * 32 + s * 8];
        }
        #pragma unroll
        for (int ni = 0; ni < 4; ++ni) {
            int n = wc * 64 + ni * 16 + (lane & 15);
            int s = (lane >> 4) ^ (n & 3);
            bb[ni] = *(const s16x8*)&Bs[buf][n * 32 + s * 8];
        }
        #pragma unroll
        for (int mi = 0; mi < 2; ++mi)
        #pragma unroll
        for (int ni = 0; ni < 4; ++ni)
            acc[mi][ni] = MFMA(av[mi], bb[ni], acc[mi][ni]);
    };

    STAGE(0, t0);
    __syncthreads();
    const int nt = t1 - t0;
    for (int t = 0; t < nt; ++t) {
        if (t + 1 < nt) STAGE((t + 1) & 1, t0 + t + 1);
        COMPUTE(t & 1);
        __syncthreads();
    }

    #pragma unroll
    for (int mi = 0; mi < 2; ++mi)
    #pragma unroll
    for (int ni = 0; ni < 4; ++ni) {
        const int col = wc * 64 + ni * 16 + (lane & 15);
        #pragma unroll
        for (int jj = 0; jj < 4; ++jj) {
            const int row = bm + wr * 32 + mi * 16 + (lane >> 4) * 4 + jj;
            Cp[((size_t)kz * 2048 + row) * 128 + col] = acc[mi][ni][jj];
        }
    }
}

// ---------------------------------------------------------------------------
// reduce 16 split-K partials + tanh -> bf16 (float4-vectorized)
// ---------------------------------------------------------------------------
__global__ __launch_bounds__(256)
void reduce_tanh(const float* __restrict__ Cp, u16* __restrict__ hout) {
    const int i4 = (blockIdx.x * 256 + threadIdx.x) * 4;   // 2048*128 elems
    const size_t S = (size_t)2048 * 128;
    float4 s = make_float4(0.f, 0.f, 0.f, 0.f);
    #pragma unroll
    for (int k = 0; k < 16; ++k) {
        float4 v = *(const float4*)&Cp[(size_t)k * S + i4];
        s.x += v.x; s.y += v.y; s.z += v.z; s.w += v.w;
    }
    uint2 o;
    o.x = (u32)f2bf(fast_tanh(s.x)) | ((u32)f2bf(fast_tanh(s.y)) << 16);
    o.y = (u32)f2bf(fast_tanh(s.z)) | ((u32)f2bf(fast_tanh(s.w)) << 16);
    *(uint2*)&hout[i4] = o;
}

// layer-3 reduce+tanh fused with trunk L4 + final combine
__global__ __launch_bounds__(256)
void reduce_out(const float* __restrict__ Cp, const u16* __restrict__ z,
                const float* __restrict__ W2, const float* __restrict__ t,
                const float* __restrict__ u, float* __restrict__ out)
{
    __shared__ float sh[4][128];
    const int wv = threadIdx.x >> 6, l = threadIdx.x & 63;
    const int b = blockIdx.x * 4 + wv;
    const size_t S = (size_t)2048 * 128;
    #pragma unroll
    for (int e = l; e < 128; e += 64) {
        float s = 0.f;
        #pragma unroll
        for (int k = 0; k < 16; ++k) s += Cp[k * S + (size_t)b * 128 + e];
        sh[wv][e] = fast_tanh(s);
    }
    __syncthreads();
    const float* wrow = &W2[(size_t)l * LDP + 33280];
    float acc = wrow[0];
    #pragma unroll 8
    for (int i = 0; i < 128; ++i) acc = fmaf(sh[wv][i], wrow[1 + i], acc);
    float p = bf2f(z[b * 64 + l]) * acc;
    #pragma unroll
    for (int off = 32; off > 0; off >>= 1) p += __shfl_down(p, off);
    if (l == 0) out[b] = u[b * 128] + t[b] * p;
}

// ---------------------------------------------------------------------------
extern "C" void kernel_launch(void* const* d_in, const int* in_sizes, int n_in,
                              void* d_out, int out_size, void* d_ws, size_t ws_size,
                              hipStream_t stream)
{
    const float* t   = (const float*)d_in[0];
    const float* u   = (const float*)d_in[1];
    const float* bw0 = (const float*)d_in[2];
    const float* bb0 = (const float*)d_in[3];
    const float* bw1 = (const float*)d_in[4];
    const float* bb1 = (const float*)d_in[5];
    const float* bw2 = (const float*)d_in[6];
    const float* bb2 = (const float*)d_in[7];
    const float* bw3 = (const float*)d_in[8];
    const float* bb3 = (const float*)d_in[9];
    const float* bw4 = (const float*)d_in[10];
    const float* bb4 = (const float*)d_in[11];
    const float* W1  = (const float*)d_in[12];
    const float* W2  = (const float*)d_in[13];
    float* out = (float*)d_out;

    // ---- workspace layout (bytes) — same as r9
    char* base = (char*)d_ws;
    u16*   bw1t = (u16*)(base);                  // 2 MB
    u16*   bw2t = (u16*)(base + 2097152);        // 2 MB
    u16*   bw3t = (u16*)(base + 4194304);        // 2 MB
    u16*   actA = (u16*)(base + 6291456);        // 4 MB
    u16*   actB = (u16*)(base + 10485760);       // 4 MB
    u16*   ubf  = (u16*)(base + 14680064);       // 512 KB
    u16*   bw0t = (u16*)(base + 15204352);       // 256 KB
    u16*   BWt  = (u16*)(base + 15499264);       // 128 KB
    float* bz   = (float*)(base + 15630336);     // 256 B
    u16*   z    = (u16*)(base + 16777216);       // 256 KB
    u16*   h1   = (u16*)(base + 17039360);       // 512 KB
    u16*   h2   = (u16*)(base + 17563648);       // 512 KB
    u16*   Bt   = (u16*)(base + 18087936);       // 4,227,072 (2 layers)
    // overlays:
    float* zc = (float*)(base);                  // 4 MB   (zgemm .. z_l1_h1)
    float* Cp = (float*)(base);                  // 16.78 MB (trunk partials)

    dim3 blk(256);
    // ---- prep0 (ubf + bw0t only)
    prep0<<<160, blk, 0, stream>>>(u, bw0, ubf, bw0t);

    // ---- branch MLP with horizontally-fused prep (128x64 GEMM tiles)
    gemm_fused<<<512, blk, 0, stream>>>(                       // L0 + T(bw1)
        ubf, 128, bw0t, 128, bb0, actA, 1024, 128, 0,
        bw1, bw1t, bw4, bb4, W1, BWt, bz, W2, Bt);
    gemm_fused<<<512, blk, 0, stream>>>(                       // L1 + T(bw2)
        actA, 1024, bw1t, 1024, bb1, actB, 1024, 1024, 1,
        bw2, bw2t, bw4, bb4, W1, BWt, bz, W2, Bt);
    gemm_fused<<<1025, blk, 0, stream>>>(                      // L2 + T(bw3) + BW + bz
        actB, 1024, bw2t, 1024, bb2, actA, 1024, 1024, 2,
        bw3, bw3t, bw4, bb4, W1, BWt, bz, W2, Bt);
    gemm_fused<<<772, blk, 0, stream>>>(                       // L3 + gather Bt
        actA, 1024, bw3t, 1024, bb3, actB, 1024, 1024, 3,
        nullptr, nullptr, bw4, bb4, W1, BWt, bz, W2, Bt);
    // ---- z partials (SK=8)
    zgemm<<<dim3(1, 32, 8), blk, 0, stream>>>(actB, BWt, zc);
    // ---- fused reduce_z + trunk L1 + h1
    z_l1_h1<<<128, blk, 0, stream>>>(zc, bz, W2, t, z, h1);
    // ---- trunk layers 2,3 (128x128 tiles, 8 waves, split-K=16)
    trunk128<<<dim3(16, 16), dim3(512), 0, stream>>>(h1, z, Bt, Cp);
    reduce_tanh<<<256, blk, 0, stream>>>(Cp, h2);
    trunk128<<<dim3(16, 16), dim3(512), 0, stream>>>(h2, z, Bt + (size_t)128 * 8256, Cp);
    // ---- layer-3 reduce + trunk L4 + combine
    reduce_out<<<512, blk, 0, stream>>>(Cp, z, W2, t, u, out);
}